// Round 1
// baseline (992.136 us; speedup 1.0000x reference)
//
#include <hip/hip_runtime.h>

#define N_NODES 100000
#define FEAT 64

__global__ void zero_kernel(float* __restrict__ p, int n) {
    int i = blockIdx.x * blockDim.x + threadIdx.x;
    int stride = gridDim.x * blockDim.x;
    for (; i < n; i += stride) p[i] = 0.0f;
}

// One 64-lane wave per edge: lane f adds feat[src][f] into agg[dst][f].
// If cnt != nullptr, lane 0 also counts the edge at dst.
__global__ __launch_bounds__(256) void scatter_kernel(
    const float* __restrict__ feat,
    const int* __restrict__ src,
    const int* __restrict__ dst,
    float* __restrict__ agg,
    float* __restrict__ cnt,
    int nEdges) {
    int wid = (blockIdx.x * blockDim.x + threadIdx.x) >> 6;
    int lane = threadIdx.x & 63;
    if (wid >= nEdges) return;
    int s = src[wid];
    int d = dst[wid];
    float v = feat[s * FEAT + lane];
    atomicAdd(&agg[d * FEAT + lane], v);
    if (cnt != nullptr && lane == 0) atomicAdd(&cnt[d], 1.0f);
}

// One wave per node: out = relu(W_l @ mean + b + W_r @ x)
// W_l, W_r staged in LDS with row stride 65 (conflict-free: bank = (65f+k)%32
// = (f+k)%32, 2 lanes/bank which is free on CDNA4).
__global__ __launch_bounds__(256) void sage_linear_kernel(
    const float* __restrict__ agg,
    const float* __restrict__ cnt,
    const float* __restrict__ xin,
    const float* __restrict__ Wl,
    const float* __restrict__ bias,
    const float* __restrict__ Wr,
    float* __restrict__ out,
    int nNodes) {
    __shared__ float sWl[64 * 65];
    __shared__ float sWr[64 * 65];
    __shared__ float sb[64];
    __shared__ float sMean[4][64];
    __shared__ float sX[4][64];

    int t = threadIdx.x;
    for (int i = t; i < 4096; i += 256) {
        int r = i >> 6, c = i & 63;
        sWl[r * 65 + c] = Wl[i];
        sWr[r * 65 + c] = Wr[i];
    }
    if (t < 64) sb[t] = bias[t];
    __syncthreads();

    int w = t >> 6;      // wave id within block (0..3)
    int lane = t & 63;   // feature index
    int node = blockIdx.x * 4 + w;
    // N_NODES % 4 == 0 and grid is exact, so no tail guard needed.
    float c = cnt[node];
    float inv = 1.0f / fmaxf(c, 1.0f);
    float meanv = agg[node * FEAT + lane] * inv;
    float xv = xin[node * FEAT + lane];
    sMean[w][lane] = meanv;
    sX[w][lane] = xv;
    __syncthreads();

    float acc = sb[lane];
    const float* wl = &sWl[lane * 65];
    const float* wr = &sWr[lane * 65];
    const float* sm = &sMean[w][0];
    const float* sx = &sX[w][0];
#pragma unroll
    for (int k = 0; k < 64; ++k) {
        acc += wl[k] * sm[k];
        acc += wr[k] * sx[k];
    }
    out[node * FEAT + lane] = fmaxf(acc, 0.0f);
}

extern "C" void kernel_launch(void* const* d_in, const int* in_sizes, int n_in,
                              void* d_out, int out_size, void* d_ws, size_t ws_size,
                              hipStream_t stream) {
    const float* x   = (const float*)d_in[0];
    const int* ei    = (const int*)d_in[1];
    const float* Wl1 = (const float*)d_in[2];
    const float* b1  = (const float*)d_in[3];
    const float* Wr1 = (const float*)d_in[4];
    const float* Wl2 = (const float*)d_in[5];
    const float* b2  = (const float*)d_in[6];
    const float* Wr2 = (const float*)d_in[7];

    const int E = in_sizes[1] / 2;   // 1,600,000
    const int* src = ei;
    const int* dst = ei + E;

    float* ws  = (float*)d_ws;
    float* agg = ws;                               // N*64 floats
    float* cnt = ws + (size_t)N_NODES * FEAT;      // N floats
    float* h   = cnt + N_NODES;                    // N*64 floats
    float* out = (float*)d_out;

    // ---- layer 1 ----
    zero_kernel<<<2048, 256, 0, stream>>>(agg, N_NODES * FEAT + N_NODES);  // agg+cnt contiguous
    scatter_kernel<<<E / 4, 256, 0, stream>>>(x, src, dst, agg, cnt, E);
    sage_linear_kernel<<<N_NODES / 4, 256, 0, stream>>>(agg, cnt, x, Wl1, b1, Wr1, h, N_NODES);

    // ---- layer 2 (cnt unchanged: same graph) ----
    zero_kernel<<<2048, 256, 0, stream>>>(agg, N_NODES * FEAT);
    scatter_kernel<<<E / 4, 256, 0, stream>>>(h, src, dst, agg, nullptr, E);
    sage_linear_kernel<<<N_NODES / 4, 256, 0, stream>>>(agg, cnt, h, Wl2, b2, Wr2, out, N_NODES);
}